// Round 5
// baseline (263.874 us; speedup 1.0000x reference)
//
#include <hip/hip_runtime.h>
#include <math.h>

#define BB 32
#define CC 2048
#define NN 784          // 28*28
#define NF4 196         // float4 per (b,c) spatial row
#define MM 4
#define LAMBDA_ 1e-3f
#define EPS_ 1e-10f
#define LOG1E4 9.210340371976184f
#define NORM_BLOCKS (BB * CC / 4)   // 16384

__device__ __forceinline__ float wred(float v) {
#pragma unroll
  for (int off = 32; off > 0; off >>= 1) v += __shfl_down(v, off, 64);
  return v;
}

// ---- K1: fused norm + partial dot (wave-private, no LDS/barriers),
//          plus peW side-blocks (blockIdx.x == NCH/4). ----
template <int NCH>
__global__ __launch_bounds__(256, 4) void k_sacc2(const float* __restrict__ x,
                                                  const float* __restrict__ W,
                                                  float* __restrict__ inv_norm,
                                                  float* __restrict__ peW,
                                                  float4* __restrict__ sPart4) {
  constexpr int CPER = CC / NCH;        // channels per wave (power of 2)
  int b    = blockIdx.y;
  int wv   = threadIdx.x >> 6;
  int lane = threadIdx.x & 63;

  if (blockIdx.x == NCH / 4) {
    // peW[m,n] = sum_c pe[n,c]*W[m,c]; this block covers a 25-wide n slice.
    const int NPS = (NN + BB - 1) / BB;   // 25
    int n0 = b * NPS, n1 = (n0 + NPS < NN) ? n0 + NPS : NN;
    int m = wv;
    for (int n = n0; n < n1; ++n) {
      float acc = 0.f;
      for (int c = lane; c < CC; c += 64) {
        float di  = __expf(-((float)(c & ~1) * (1.f / CC)) * LOG1E4);
        float arg = (float)n * di;
        float pe  = (c & 1) ? __cosf(arg) : __sinf(arg);
        acc += pe * W[m * CC + c];
      }
      acc = wred(acc);
      if (lane == 0) peW[m * NN + n] = acc;
    }
    return;
  }

  int ch = blockIdx.x * 4 + wv;
  int c0 = ch * CPER;
  const float4* xb = (const float4*)(x + ((size_t)b * CC + c0) * NN);
  const float4 z = make_float4(0.f, 0.f, 0.f, 0.f);

  float4 acc[MM][4];
#pragma unroll
  for (int m = 0; m < MM; ++m)
#pragma unroll
    for (int j = 0; j < 4; ++j) acc[m][j] = z;

  float4 xA[4], xB[4];

  auto LOAD = [&](float4* dst, int i) {
    const float4* p = xb + (size_t)i * NF4 + lane;
    dst[0] = p[0];
    dst[1] = p[64];
    dst[2] = p[128];
    dst[3] = (lane < (NF4 - 192)) ? p[192] : z;   // lanes 0..3 only
  };
  auto COMP = [&](const float4* v, int i) {
    int c = c0 + i;
    float sq = v[0].x * v[0].x + v[0].y * v[0].y + v[0].z * v[0].z + v[0].w * v[0].w
             + v[1].x * v[1].x + v[1].y * v[1].y + v[1].z * v[1].z + v[1].w * v[1].w
             + v[2].x * v[2].x + v[2].y * v[2].y + v[2].z * v[2].z + v[2].w * v[2].w
             + v[3].x * v[3].x + v[3].y * v[3].y + v[3].z * v[3].z + v[3].w * v[3].w;
#pragma unroll
    for (int o = 1; o < 64; o <<= 1) sq += __shfl_xor(sq, o, 64);
    float inv = 1.f / fmaxf(sqrtf(sq), EPS_);
    if (lane == 0) inv_norm[b * CC + c] = inv;
    float w0 = inv * W[0 * CC + c];
    float w1 = inv * W[1 * CC + c];
    float w2 = inv * W[2 * CC + c];
    float w3 = inv * W[3 * CC + c];
#pragma unroll
    for (int j = 0; j < 4; ++j) {
      float4 v4 = v[j];
      acc[0][j].x += v4.x * w0; acc[0][j].y += v4.y * w0; acc[0][j].z += v4.z * w0; acc[0][j].w += v4.w * w0;
      acc[1][j].x += v4.x * w1; acc[1][j].y += v4.y * w1; acc[1][j].z += v4.z * w1; acc[1][j].w += v4.w * w1;
      acc[2][j].x += v4.x * w2; acc[2][j].y += v4.y * w2; acc[2][j].z += v4.z * w2; acc[2][j].w += v4.w * w2;
      acc[3][j].x += v4.x * w3; acc[3][j].y += v4.y * w3; acc[3][j].z += v4.z * w3; acc[3][j].w += v4.w * w3;
    }
  };

  LOAD(xA, 0);
  for (int i = 0; i < CPER; i += 2) {
    LOAD(xB, i + 1);
    COMP(xA, i);
    LOAD(xA, (i + 2) & (CPER - 1));   // wraps to 0 on last iter (harmless reload)
    COMP(xB, i + 1);
  }

  size_t base = (((size_t)b * NCH + ch) * MM) * NF4;
#pragma unroll
  for (int m = 0; m < MM; ++m)
#pragma unroll
    for (int j = 0; j < 4; ++j) {
      int f = lane + 64 * j;
      if (f < NF4) sPart4[base + (size_t)m * NF4 + f] = acc[m][j];
    }
}

// ---- K2: hid4[(b*N+n)*4+m] = sigmoid(peW + sum_ch sPart) ----
template <int NCH>
__global__ __launch_bounds__(256) void k_hid(const float* __restrict__ sPart,
                                             const float* __restrict__ peW,
                                             float* __restrict__ hid4) {
  int n = blockIdx.x * 256 + threadIdx.x;
  int b = blockIdx.y;
  if (n >= NN) return;
  float h[MM];
#pragma unroll
  for (int m = 0; m < MM; ++m) {
    float s = peW[m * NN + n];
#pragma unroll 8
    for (int ch = 0; ch < NCH; ++ch)
      s += sPart[(((size_t)b * NCH + ch) * MM + m) * NN + n];
    h[m] = 1.f / (1.f + __expf(-s));
  }
  float4 hv = make_float4(h[0], h[1], h[2], h[3]);
  *(float4*)(hid4 + ((size_t)b * NN + n) * 4) = hv;
}

// ---- K3: out[b,c] = sum_m (inv*aX[m] + aP[m]) / (aD[m]+lambda) ----
__global__ __launch_bounds__(256) void k_out(const float* __restrict__ x,
                                             const float* __restrict__ hid4,
                                             const float* __restrict__ inv_norm,
                                             float* __restrict__ out) {
  int idx  = blockIdx.x * 4 + (threadIdx.x >> 6);   // (b*C+c)
  int lane = threadIdx.x & 63;
  int b = idx >> 11;
  int c = idx & (CC - 1);
  const float4* row = (const float4*)(x + (size_t)idx * NN);
  const float4* hb  = (const float4*)(hid4 + (size_t)b * NN * 4);
  float di = __expf(-((float)(c & ~1) * (1.0f / CC)) * LOG1E4);
  bool use_sin = !(c & 1);
  float aX0=0,aX1=0,aX2=0,aX3=0, aP0=0,aP1=0,aP2=0,aP3=0, aD0=0,aD1=0,aD2=0,aD3=0;
  for (int f = lane; f < NF4; f += 64) {
    float4 xv = row[f];
    int n = f * 4;
    float4 h0 = hb[n + 0], h1 = hb[n + 1], h2 = hb[n + 2], h3 = hb[n + 3];
    float a0 = (float)(n + 0) * di, a1 = (float)(n + 1) * di;
    float a2 = (float)(n + 2) * di, a3 = (float)(n + 3) * di;
    float p0 = use_sin ? __sinf(a0) : __cosf(a0);
    float p1 = use_sin ? __sinf(a1) : __cosf(a1);
    float p2 = use_sin ? __sinf(a2) : __cosf(a2);
    float p3 = use_sin ? __sinf(a3) : __cosf(a3);
    aX0 += xv.x*h0.x + xv.y*h1.x + xv.z*h2.x + xv.w*h3.x;
    aX1 += xv.x*h0.y + xv.y*h1.y + xv.z*h2.y + xv.w*h3.y;
    aX2 += xv.x*h0.z + xv.y*h1.z + xv.z*h2.z + xv.w*h3.z;
    aX3 += xv.x*h0.w + xv.y*h1.w + xv.z*h2.w + xv.w*h3.w;
    aP0 += p0*h0.x + p1*h1.x + p2*h2.x + p3*h3.x;
    aP1 += p0*h0.y + p1*h1.y + p2*h2.y + p3*h3.y;
    aP2 += p0*h0.z + p1*h1.z + p2*h2.z + p3*h3.z;
    aP3 += p0*h0.w + p1*h1.w + p2*h2.w + p3*h3.w;
    aD0 += h0.x*h0.x + h1.x*h1.x + h2.x*h2.x + h3.x*h3.x;
    aD1 += h0.y*h0.y + h1.y*h1.y + h2.y*h2.y + h3.y*h3.y;
    aD2 += h0.z*h0.z + h1.z*h1.z + h2.z*h2.z + h3.z*h3.z;
    aD3 += h0.w*h0.w + h1.w*h1.w + h2.w*h2.w + h3.w*h3.w;
  }
  aX0 = wred(aX0); aX1 = wred(aX1); aX2 = wred(aX2); aX3 = wred(aX3);
  aP0 = wred(aP0); aP1 = wred(aP1); aP2 = wred(aP2); aP3 = wred(aP3);
  aD0 = wred(aD0); aD1 = wred(aD1); aD2 = wred(aD2); aD3 = wred(aD3);
  if (lane == 0) {
    float inv = inv_norm[idx];
    float r = (inv * aX0 + aP0) / (aD0 + LAMBDA_)
            + (inv * aX1 + aP1) / (aD1 + LAMBDA_)
            + (inv * aX2 + aP2) / (aD2 + LAMBDA_)
            + (inv * aX3 + aP3) / (aD3 + LAMBDA_);
    if (isnan(r)) r = 0.f;
    else if (isinf(r)) r = (r > 0.f) ? 3.4028234663852886e38f : -3.4028234663852886e38f;
    out[idx] = r;
  }
}

extern "C" void kernel_launch(void* const* d_in, const int* in_sizes, int n_in,
                              void* d_out, int out_size, void* d_ws, size_t ws_size,
                              hipStream_t stream) {
  const float* x = (const float*)d_in[0];   // (B, C, S, S)
  const float* W = (const float*)d_in[1];   // (M, C, 1)
  float* out = (float*)d_out;               // (B, 1, C)
  float* ws  = (float*)d_ws;

  float* inv_norm = ws;                                   // B*C   = 65536
  float* peW      = inv_norm + (size_t)BB * CC;           // M*N   = 3136
  float* hid4     = peW + (size_t)MM * NN;                // B*N*M = 401408
  float* sPart    = hid4 + (size_t)BB * NN * MM;          // B*NCH*M*N

  const size_t base_floats = (size_t)BB * CC + MM * NN + (size_t)BB * NN * MM;
  const size_t need128 = (base_floats + (size_t)BB * 128 * MM * NN) * sizeof(float);
  const size_t need64  = (base_floats + (size_t)BB * 64 * MM * NN) * sizeof(float);

  if (ws_size >= need128) {
    k_sacc2<128><<<dim3(33, BB), 256, 0, stream>>>(x, W, inv_norm, peW, (float4*)sPart);
    k_hid<128><<<dim3(4, BB), 256, 0, stream>>>(sPart, peW, hid4);
  } else if (ws_size >= need64) {
    k_sacc2<64><<<dim3(17, BB), 256, 0, stream>>>(x, W, inv_norm, peW, (float4*)sPart);
    k_hid<64><<<dim3(4, BB), 256, 0, stream>>>(sPart, peW, hid4);
  } else {
    k_sacc2<32><<<dim3(9, BB), 256, 0, stream>>>(x, W, inv_norm, peW, (float4*)sPart);
    k_hid<32><<<dim3(4, BB), 256, 0, stream>>>(sPart, peW, hid4);
  }
  k_out<<<NORM_BLOCKS, 256, 0, stream>>>(x, hid4, inv_norm, out);
}

// Round 6
// 217.803 us; speedup vs baseline: 1.2115x; 1.2115x over previous
//
#include <hip/hip_runtime.h>
#include <math.h>

#define BB 32
#define CC 2048
#define NN 784          // 28*28
#define NF4 196         // float4 per (b,c) spatial row
#define MM 4
#define LAMBDA_ 1e-3f
#define EPS_ 1e-10f
#define LOG1E4 9.210340371976184f
#define NORM_BLOCKS (BB * CC / 4)   // 16384

__device__ __forceinline__ float wred(float v) {
#pragma unroll
  for (int off = 32; off > 0; off >>= 1) v += __shfl_down(v, off, 64);
  return v;
}

// ---- K1: fused norm + partial dot (wave-private, no LDS/barriers),
//          plus peW side-blocks (blockIdx.x == NCH/4).
//          VGPR budget: acc 64 + xA/xB 32 + misc ~20 = ~115 -> cap 128 (2 w/EU
//          -> 4 waves/SIMD via 4-wave blocks). DO NOT cap lower: 64 spills. ----
template <int NCH>
__global__ __launch_bounds__(256, 2) void k_sacc2(const float* __restrict__ x,
                                                  const float* __restrict__ W,
                                                  float* __restrict__ inv_norm,
                                                  float* __restrict__ peW,
                                                  float4* __restrict__ sPart4) {
  constexpr int CPER = CC / NCH;        // channels per wave (power of 2)
  int b    = blockIdx.y;
  int wv   = threadIdx.x >> 6;
  int lane = threadIdx.x & 63;

  if (blockIdx.x == NCH / 4) {
    // peW[m,n] = sum_c pe[n,c]*W[m,c]; this block covers a 25-wide n slice.
    const int NPS = (NN + BB - 1) / BB;   // 25
    int n0 = b * NPS, n1 = (n0 + NPS < NN) ? n0 + NPS : NN;
    int m = wv;
    for (int n = n0; n < n1; ++n) {
      float acc = 0.f;
      for (int c = lane; c < CC; c += 64) {
        float di  = __expf(-((float)(c & ~1) * (1.f / CC)) * LOG1E4);
        float arg = (float)n * di;
        float pe  = (c & 1) ? __cosf(arg) : __sinf(arg);
        acc += pe * W[m * CC + c];
      }
      acc = wred(acc);
      if (lane == 0) peW[m * NN + n] = acc;
    }
    return;
  }

  int ch = blockIdx.x * 4 + wv;
  int c0 = ch * CPER;
  const float4* xb = (const float4*)(x + ((size_t)b * CC + c0) * NN);
  const float4 z = make_float4(0.f, 0.f, 0.f, 0.f);

  float4 acc[MM][4];
#pragma unroll
  for (int m = 0; m < MM; ++m)
#pragma unroll
    for (int j = 0; j < 4; ++j) acc[m][j] = z;

  float4 xA[4], xB[4];

  auto LOAD = [&](float4* dst, int i) {
    const float4* p = xb + (size_t)i * NF4 + lane;
    dst[0] = p[0];
    dst[1] = p[64];
    dst[2] = p[128];
    dst[3] = (lane < (NF4 - 192)) ? p[192] : z;   // lanes 0..3 only
  };
  auto COMP = [&](const float4* v, int i) {
    int c = c0 + i;
    float sq = v[0].x * v[0].x + v[0].y * v[0].y + v[0].z * v[0].z + v[0].w * v[0].w
             + v[1].x * v[1].x + v[1].y * v[1].y + v[1].z * v[1].z + v[1].w * v[1].w
             + v[2].x * v[2].x + v[2].y * v[2].y + v[2].z * v[2].z + v[2].w * v[2].w
             + v[3].x * v[3].x + v[3].y * v[3].y + v[3].z * v[3].z + v[3].w * v[3].w;
#pragma unroll
    for (int o = 1; o < 64; o <<= 1) sq += __shfl_xor(sq, o, 64);
    float inv = 1.f / fmaxf(sqrtf(sq), EPS_);
    if (lane == 0) inv_norm[b * CC + c] = inv;
    float w0 = inv * W[0 * CC + c];
    float w1 = inv * W[1 * CC + c];
    float w2 = inv * W[2 * CC + c];
    float w3 = inv * W[3 * CC + c];
#pragma unroll
    for (int j = 0; j < 4; ++j) {
      float4 v4 = v[j];
      acc[0][j].x += v4.x * w0; acc[0][j].y += v4.y * w0; acc[0][j].z += v4.z * w0; acc[0][j].w += v4.w * w0;
      acc[1][j].x += v4.x * w1; acc[1][j].y += v4.y * w1; acc[1][j].z += v4.z * w1; acc[1][j].w += v4.w * w1;
      acc[2][j].x += v4.x * w2; acc[2][j].y += v4.y * w2; acc[2][j].z += v4.z * w2; acc[2][j].w += v4.w * w2;
      acc[3][j].x += v4.x * w3; acc[3][j].y += v4.y * w3; acc[3][j].z += v4.z * w3; acc[3][j].w += v4.w * w3;
    }
  };

  LOAD(xA, 0);
  for (int i = 0; i < CPER; i += 2) {
    LOAD(xB, i + 1);
    COMP(xA, i);
    LOAD(xA, (i + 2) & (CPER - 1));   // wraps to 0 on last iter (harmless reload)
    COMP(xB, i + 1);
  }

  size_t base = (((size_t)b * NCH + ch) * MM) * NF4;
#pragma unroll
  for (int m = 0; m < MM; ++m)
#pragma unroll
    for (int j = 0; j < 4; ++j) {
      int f = lane + 64 * j;
      if (f < NF4) sPart4[base + (size_t)m * NF4 + f] = acc[m][j];
    }
}

// ---- K2: hid4[(b*N+n)*4+m] = sigmoid(peW + sum_ch sPart) ----
template <int NCH>
__global__ __launch_bounds__(256) void k_hid(const float* __restrict__ sPart,
                                             const float* __restrict__ peW,
                                             float* __restrict__ hid4) {
  int n = blockIdx.x * 256 + threadIdx.x;
  int b = blockIdx.y;
  if (n >= NN) return;
  float h[MM];
#pragma unroll
  for (int m = 0; m < MM; ++m) {
    float s = peW[m * NN + n];
#pragma unroll 8
    for (int ch = 0; ch < NCH; ++ch)
      s += sPart[(((size_t)b * NCH + ch) * MM + m) * NN + n];
    h[m] = 1.f / (1.f + __expf(-s));
  }
  float4 hv = make_float4(h[0], h[1], h[2], h[3]);
  *(float4*)(hid4 + ((size_t)b * NN + n) * 4) = hv;
}

// ---- K3: out[b,c] = sum_m (inv*aX[m] + aP[m]) / (aD[m]+lambda) ----
__global__ __launch_bounds__(256) void k_out(const float* __restrict__ x,
                                             const float* __restrict__ hid4,
                                             const float* __restrict__ inv_norm,
                                             float* __restrict__ out) {
  int idx  = blockIdx.x * 4 + (threadIdx.x >> 6);   // (b*C+c)
  int lane = threadIdx.x & 63;
  int b = idx >> 11;
  int c = idx & (CC - 1);
  const float4* row = (const float4*)(x + (size_t)idx * NN);
  const float4* hb  = (const float4*)(hid4 + (size_t)b * NN * 4);
  float di = __expf(-((float)(c & ~1) * (1.0f / CC)) * LOG1E4);
  bool use_sin = !(c & 1);
  float aX0=0,aX1=0,aX2=0,aX3=0, aP0=0,aP1=0,aP2=0,aP3=0, aD0=0,aD1=0,aD2=0,aD3=0;
  for (int f = lane; f < NF4; f += 64) {
    float4 xv = row[f];
    int n = f * 4;
    float4 h0 = hb[n + 0], h1 = hb[n + 1], h2 = hb[n + 2], h3 = hb[n + 3];
    float a0 = (float)(n + 0) * di, a1 = (float)(n + 1) * di;
    float a2 = (float)(n + 2) * di, a3 = (float)(n + 3) * di;
    float p0 = use_sin ? __sinf(a0) : __cosf(a0);
    float p1 = use_sin ? __sinf(a1) : __cosf(a1);
    float p2 = use_sin ? __sinf(a2) : __cosf(a2);
    float p3 = use_sin ? __sinf(a3) : __cosf(a3);
    aX0 += xv.x*h0.x + xv.y*h1.x + xv.z*h2.x + xv.w*h3.x;
    aX1 += xv.x*h0.y + xv.y*h1.y + xv.z*h2.y + xv.w*h3.y;
    aX2 += xv.x*h0.z + xv.y*h1.z + xv.z*h2.z + xv.w*h3.z;
    aX3 += xv.x*h0.w + xv.y*h1.w + xv.z*h2.w + xv.w*h3.w;
    aP0 += p0*h0.x + p1*h1.x + p2*h2.x + p3*h3.x;
    aP1 += p0*h0.y + p1*h1.y + p2*h2.y + p3*h3.y;
    aP2 += p0*h0.z + p1*h1.z + p2*h2.z + p3*h3.z;
    aP3 += p0*h0.w + p1*h1.w + p2*h2.w + p3*h3.w;
    aD0 += h0.x*h0.x + h1.x*h1.x + h2.x*h2.x + h3.x*h3.x;
    aD1 += h0.y*h0.y + h1.y*h1.y + h2.y*h2.y + h3.y*h3.y;
    aD2 += h0.z*h0.z + h1.z*h1.z + h2.z*h2.z + h3.z*h3.z;
    aD3 += h0.w*h0.w + h1.w*h1.w + h2.w*h2.w + h3.w*h3.w;
  }
  aX0 = wred(aX0); aX1 = wred(aX1); aX2 = wred(aX2); aX3 = wred(aX3);
  aP0 = wred(aP0); aP1 = wred(aP1); aP2 = wred(aP2); aP3 = wred(aP3);
  aD0 = wred(aD0); aD1 = wred(aD1); aD2 = wred(aD2); aD3 = wred(aD3);
  if (lane == 0) {
    float inv = inv_norm[idx];
    float r = (inv * aX0 + aP0) / (aD0 + LAMBDA_)
            + (inv * aX1 + aP1) / (aD1 + LAMBDA_)
            + (inv * aX2 + aP2) / (aD2 + LAMBDA_)
            + (inv * aX3 + aP3) / (aD3 + LAMBDA_);
    if (isnan(r)) r = 0.f;
    else if (isinf(r)) r = (r > 0.f) ? 3.4028234663852886e38f : -3.4028234663852886e38f;
    out[idx] = r;
  }
}

extern "C" void kernel_launch(void* const* d_in, const int* in_sizes, int n_in,
                              void* d_out, int out_size, void* d_ws, size_t ws_size,
                              hipStream_t stream) {
  const float* x = (const float*)d_in[0];   // (B, C, S, S)
  const float* W = (const float*)d_in[1];   // (M, C, 1)
  float* out = (float*)d_out;               // (B, 1, C)
  float* ws  = (float*)d_ws;

  float* inv_norm = ws;                                   // B*C   = 65536
  float* peW      = inv_norm + (size_t)BB * CC;           // M*N   = 3136
  float* hid4     = peW + (size_t)MM * NN;                // B*N*M = 401408
  float* sPart    = hid4 + (size_t)BB * NN * MM;          // B*NCH*M*N

  const size_t base_floats = (size_t)BB * CC + MM * NN + (size_t)BB * NN * MM;
  const size_t need128 = (base_floats + (size_t)BB * 128 * MM * NN) * sizeof(float);
  const size_t need64  = (base_floats + (size_t)BB * 64 * MM * NN) * sizeof(float);

  if (ws_size >= need128) {
    k_sacc2<128><<<dim3(33, BB), 256, 0, stream>>>(x, W, inv_norm, peW, (float4*)sPart);
    k_hid<128><<<dim3(4, BB), 256, 0, stream>>>(sPart, peW, hid4);
  } else if (ws_size >= need64) {
    k_sacc2<64><<<dim3(17, BB), 256, 0, stream>>>(x, W, inv_norm, peW, (float4*)sPart);
    k_hid<64><<<dim3(4, BB), 256, 0, stream>>>(sPart, peW, hid4);
  } else {
    k_sacc2<32><<<dim3(9, BB), 256, 0, stream>>>(x, W, inv_norm, peW, (float4*)sPart);
    k_hid<32><<<dim3(4, BB), 256, 0, stream>>>(sPart, peW, hid4);
  }
  k_out<<<NORM_BLOCKS, 256, 0, stream>>>(x, hid4, inv_norm, out);
}

// Round 7
// 144.686 us; speedup vs baseline: 1.8238x; 1.5054x over previous
//
#include <hip/hip_runtime.h>
#include <math.h>

#define BB 32
#define CC 2048
#define NN 784          // 28*28
#define NF4 196         // float4 per (b,c) spatial row
#define MM 4
#define NCH 32          // channel chunks for the dot pass
#define CPER (CC / NCH) // 64 channels per block
#define LAMBDA_ 1e-3f
#define EPS_ 1e-10f
#define LOG1E4 9.210340371976184f
#define NORMB (BB * CC / 4)         // 4096 blocks, 4 row-waves each
#define OUT_BLOCKS (BB * CC / 4)    // 16384 (wave per row)

__device__ __forceinline__ float wred(float v) {
#pragma unroll
  for (int off = 32; off > 0; off >>= 1) v += __shfl_down(v, off, 64);
  return v;
}

// ---- K1: wave-per-row norm -> inv_norm + pre-scaled weights Ws[b,m,c];
//          peW side-blocks (bid >= NORMB). No LDS, no barriers. ----
__global__ __launch_bounds__(256) void k_norm_w(const float* __restrict__ x,
                                                const float* __restrict__ W,
                                                float* __restrict__ inv_norm,
                                                float* __restrict__ Ws,
                                                float* __restrict__ peW) {
  int bid  = blockIdx.x;
  int wv   = threadIdx.x >> 6;
  int lane = threadIdx.x & 63;

  if (bid >= NORMB) {
    // peW[m,n] = sum_c pe[n,c]*W[m,c]; one n per block, wave per m.
    int n = bid - NORMB;
    int m = wv;
    float acc = 0.f;
    for (int c = lane; c < CC; c += 64) {
      float di  = __expf(-((float)(c & ~1) * (1.f / CC)) * LOG1E4);
      float arg = (float)n * di;
      float pe  = (c & 1) ? __cosf(arg) : __sinf(arg);
      acc += pe * W[m * CC + c];
    }
    acc = wred(acc);
    if (lane == 0) peW[m * NN + n] = acc;
    return;
  }

  int idx = bid * 4 + wv;            // (b*C+c)
  int b = idx >> 11;
  int c = idx & (CC - 1);
  const float4* row = (const float4*)(x + (size_t)idx * NN);
  float4 v0 = row[lane];
  float4 v1 = row[lane + 64];
  float4 v2 = row[lane + 128];
  float4 v3 = (lane < (NF4 - 192)) ? row[lane + 192] : make_float4(0.f, 0.f, 0.f, 0.f);
  float ss = v0.x*v0.x + v0.y*v0.y + v0.z*v0.z + v0.w*v0.w
           + v1.x*v1.x + v1.y*v1.y + v1.z*v1.z + v1.w*v1.w
           + v2.x*v2.x + v2.y*v2.y + v2.z*v2.z + v2.w*v2.w
           + v3.x*v3.x + v3.y*v3.y + v3.z*v3.z + v3.w*v3.w;
  ss = wred(ss);
  if (lane == 0) {
    float inv = 1.f / fmaxf(sqrtf(ss), EPS_);
    inv_norm[idx] = inv;
#pragma unroll
    for (int m = 0; m < MM; ++m)
      Ws[((size_t)b * MM + m) * CC + c] = W[m * CC + c] * inv;
  }
}

// ---- K2: partial dot, thread-per-pixel-float4, serial channels.
//          No shfl/LDS/barriers; 8-deep load buffer for MLP. ----
__global__ __launch_bounds__(256) void k_sacc3(const float* __restrict__ x,
                                               const float* __restrict__ Ws,
                                               float4* __restrict__ sPart4) {
  int t  = threadIdx.x;          // float4 index within row
  int ch = blockIdx.x;
  int b  = blockIdx.y;
  if (t >= NF4) return;
  int c0 = ch * CPER;
  const float4* xb = (const float4*)(x + ((size_t)b * CC + c0) * NN) + t;
  const float* wb  = Ws + (size_t)b * MM * CC + c0;

  float4 a0{0,0,0,0}, a1{0,0,0,0}, a2{0,0,0,0}, a3{0,0,0,0};

  for (int i = 0; i < CPER; i += 8) {
    float4 xv[8];
#pragma unroll
    for (int u = 0; u < 8; ++u) xv[u] = xb[(size_t)(i + u) * NF4];
#pragma unroll
    for (int u = 0; u < 8; ++u) {
      int c = i + u;
      float w0 = wb[0 * CC + c];
      float w1 = wb[1 * CC + c];
      float w2 = wb[2 * CC + c];
      float w3 = wb[3 * CC + c];
      float4 v = xv[u];
      a0.x += v.x * w0; a0.y += v.y * w0; a0.z += v.z * w0; a0.w += v.w * w0;
      a1.x += v.x * w1; a1.y += v.y * w1; a1.z += v.z * w1; a1.w += v.w * w1;
      a2.x += v.x * w2; a2.y += v.y * w2; a2.z += v.z * w2; a2.w += v.w * w2;
      a3.x += v.x * w3; a3.y += v.y * w3; a3.z += v.z * w3; a3.w += v.w * w3;
    }
  }
  size_t base = (((size_t)b * NCH + ch) * MM) * NF4 + t;
  sPart4[base + 0 * NF4] = a0;
  sPart4[base + 1 * NF4] = a1;
  sPart4[base + 2 * NF4] = a2;
  sPart4[base + 3 * NF4] = a3;
}

// ---- K3: hid4[(b*N+n)*4+m] = sigmoid(peW + sum_ch sPart) ----
__global__ __launch_bounds__(256) void k_hid(const float* __restrict__ sPart,
                                             const float* __restrict__ peW,
                                             float* __restrict__ hid4) {
  int n = blockIdx.x * 256 + threadIdx.x;
  int b = blockIdx.y;
  if (n >= NN) return;
  float h[MM];
#pragma unroll
  for (int m = 0; m < MM; ++m) {
    float s = peW[m * NN + n];
#pragma unroll 8
    for (int ch = 0; ch < NCH; ++ch)
      s += sPart[(((size_t)b * NCH + ch) * MM + m) * NN + n];
    h[m] = 1.f / (1.f + __expf(-s));
  }
  float4 hv = make_float4(h[0], h[1], h[2], h[3]);
  *(float4*)(hid4 + ((size_t)b * NN + n) * 4) = hv;
}

// ---- K4: out[b,c] = sum_m (inv*aX[m] + aP[m]) / (aD[m]+lambda) ----
__global__ __launch_bounds__(256) void k_out(const float* __restrict__ x,
                                             const float* __restrict__ hid4,
                                             const float* __restrict__ inv_norm,
                                             float* __restrict__ out) {
  int idx  = blockIdx.x * 4 + (threadIdx.x >> 6);   // (b*C+c)
  int lane = threadIdx.x & 63;
  int b = idx >> 11;
  int c = idx & (CC - 1);
  const float4* row = (const float4*)(x + (size_t)idx * NN);
  const float4* hb  = (const float4*)(hid4 + (size_t)b * NN * 4);
  float di = __expf(-((float)(c & ~1) * (1.0f / CC)) * LOG1E4);
  bool use_sin = !(c & 1);
  float aX0=0,aX1=0,aX2=0,aX3=0, aP0=0,aP1=0,aP2=0,aP3=0, aD0=0,aD1=0,aD2=0,aD3=0;
  for (int f = lane; f < NF4; f += 64) {
    float4 xv = row[f];
    int n = f * 4;
    float4 h0 = hb[n + 0], h1 = hb[n + 1], h2 = hb[n + 2], h3 = hb[n + 3];
    float a0 = (float)(n + 0) * di, a1 = (float)(n + 1) * di;
    float a2 = (float)(n + 2) * di, a3 = (float)(n + 3) * di;
    float p0 = use_sin ? __sinf(a0) : __cosf(a0);
    float p1 = use_sin ? __sinf(a1) : __cosf(a1);
    float p2 = use_sin ? __sinf(a2) : __cosf(a2);
    float p3 = use_sin ? __sinf(a3) : __cosf(a3);
    aX0 += xv.x*h0.x + xv.y*h1.x + xv.z*h2.x + xv.w*h3.x;
    aX1 += xv.x*h0.y + xv.y*h1.y + xv.z*h2.y + xv.w*h3.y;
    aX2 += xv.x*h0.z + xv.y*h1.z + xv.z*h2.z + xv.w*h3.z;
    aX3 += xv.x*h0.w + xv.y*h1.w + xv.z*h2.w + xv.w*h3.w;
    aP0 += p0*h0.x + p1*h1.x + p2*h2.x + p3*h3.x;
    aP1 += p0*h0.y + p1*h1.y + p2*h2.y + p3*h3.y;
    aP2 += p0*h0.z + p1*h1.z + p2*h2.z + p3*h3.z;
    aP3 += p0*h0.w + p1*h1.w + p2*h2.w + p3*h3.w;
    aD0 += h0.x*h0.x + h1.x*h1.x + h2.x*h2.x + h3.x*h3.x;
    aD1 += h0.y*h0.y + h1.y*h1.y + h2.y*h2.y + h3.y*h3.y;
    aD2 += h0.z*h0.z + h1.z*h1.z + h2.z*h2.z + h3.z*h3.z;
    aD3 += h0.w*h0.w + h1.w*h1.w + h2.w*h2.w + h3.w*h3.w;
  }
  aX0 = wred(aX0); aX1 = wred(aX1); aX2 = wred(aX2); aX3 = wred(aX3);
  aP0 = wred(aP0); aP1 = wred(aP1); aP2 = wred(aP2); aP3 = wred(aP3);
  aD0 = wred(aD0); aD1 = wred(aD1); aD2 = wred(aD2); aD3 = wred(aD3);
  if (lane == 0) {
    float inv = inv_norm[idx];
    float r = (inv * aX0 + aP0) / (aD0 + LAMBDA_)
            + (inv * aX1 + aP1) / (aD1 + LAMBDA_)
            + (inv * aX2 + aP2) / (aD2 + LAMBDA_)
            + (inv * aX3 + aP3) / (aD3 + LAMBDA_);
    if (isnan(r)) r = 0.f;
    else if (isinf(r)) r = (r > 0.f) ? 3.4028234663852886e38f : -3.4028234663852886e38f;
    out[idx] = r;
  }
}

extern "C" void kernel_launch(void* const* d_in, const int* in_sizes, int n_in,
                              void* d_out, int out_size, void* d_ws, size_t ws_size,
                              hipStream_t stream) {
  const float* x = (const float*)d_in[0];   // (B, C, S, S)
  const float* W = (const float*)d_in[1];   // (M, C, 1)
  float* out = (float*)d_out;               // (B, 1, C)
  float* ws  = (float*)d_ws;

  float* inv_norm = ws;                                   // B*C        = 65536
  float* peW      = inv_norm + (size_t)BB * CC;           // M*N        = 3136
  float* hid4     = peW + (size_t)MM * NN;                // B*N*M      = 401408
  float* Ws       = hid4 + (size_t)BB * NN * MM;          // B*M*C      = 262144
  float* sPart    = Ws + (size_t)BB * MM * CC;            // B*NCH*M*N  = 3.2M floats

  k_norm_w<<<NORMB + NN, 256, 0, stream>>>(x, W, inv_norm, Ws, peW);
  k_sacc3<<<dim3(NCH, BB), 256, 0, stream>>>(x, Ws, (float4*)sPart);
  k_hid<<<dim3(4, BB), 256, 0, stream>>>(sPart, peW, hid4);
  k_out<<<OUT_BLOCKS, 256, 0, stream>>>(x, hid4, inv_norm, out);
}